// Round 1
// baseline (79.995 us; speedup 1.0000x reference)
//
#include <hip/hip_runtime.h>

// SidewaysTime: out = concat(flat, tril(outer(flat,flat))) per batch sample.
// B=32, N=2048 (=128*16). Output = 32 * (2048 + 2048*2049/2) fp32 = 268.8 MB.
// Pure store-bandwidth bound; index math is cheap relative to 6.3 TB/s.

#define BATCH      32
#define NFEAT      2048
#define TRI_COUNT  (NFEAT * (NFEAT + 1) / 2)      // 2,098,176
#define PER_BATCH  (NFEAT + TRI_COUNT)            // 2,100,224 (divisible by 4)
#define TOTAL_ELEM (BATCH * PER_BATCH)            // 67,207,168
#define TOTAL4     (TOTAL_ELEM / 4)               // 16,801,792

__device__ __forceinline__ int tri(int i) { return (i * (i + 1)) >> 1; }

__global__ void __launch_bounds__(256)
sideways_kernel(const float* __restrict__ in, float* __restrict__ out) {
    const int stride = gridDim.x * blockDim.x;
    for (int idx4 = blockIdx.x * blockDim.x + threadIdx.x; idx4 < TOTAL4;
         idx4 += stride) {
        const int base = idx4 << 2;                    // element index, fits int32
        const int b    = base / PER_BATCH;             // magic-mul, cheap
        const int rem  = base - b * PER_BATCH;
        const float* __restrict__ f = in + b * NFEAT;

        float4 o;
        if (rem < NFEAT) {
            // linear part: straight aligned copy (rem % 4 == 0, NFEAT % 4 == 0)
            o = *reinterpret_cast<const float4*>(f + rem);
        } else {
            const int t0 = rem - NFEAT;                // tril flat index, row-major
            // largest i with tri(i) <= t0;  i ~ (sqrt(8t+1)-1)/2
            int i = (int)((sqrtf((float)(8 * t0) + 1.0f) - 1.0f) * 0.5f);
            if (i < 0) i = 0;
            if (i > NFEAT - 1) i = NFEAT - 1;
            while (tri(i) > t0) --i;                   // exact integer fixup
            while (tri(i + 1) <= t0) ++i;

            float ov[4];
            int t = t0;
#pragma unroll
            for (int k = 0; k < 4; ++k, ++t) {
                while (tri(i + 1) <= t) ++i;           // may cross rows (short early rows)
                const int j = t - tri(i);
                ov[k] = f[i] * f[j];
            }
            o = make_float4(ov[0], ov[1], ov[2], ov[3]);
        }
        *reinterpret_cast<float4*>(out + base) = o;
    }
}

extern "C" void kernel_launch(void* const* d_in, const int* in_sizes, int n_in,
                              void* d_out, int out_size, void* d_ws, size_t ws_size,
                              hipStream_t stream) {
    const float* in  = (const float*)d_in[0];
    float*       out = (float*)d_out;
    // memory-bound: ~2048-4096 blocks + grid-stride (Guideline 11)
    const int block = 256;
    const int grid  = 4096;
    hipLaunchKernelGGL(sideways_kernel, dim3(grid), dim3(block), 0, stream, in, out);
}

// Round 2
// 46.465 us; speedup vs baseline: 1.7216x; 1.7216x over previous
//
#include <hip/hip_runtime.h>

// SidewaysTime: out = concat(flat, tril(outer(flat,flat))) per batch sample.
// B=32, N=2048. Output = 32 * (2048 + 2048*2049/2) fp32 = 268.8 MB -> pure
// store-BW bound (fill ceiling measured at 6.7-6.9 TB/s on this harness).
//
// Row-based mapping: tril row i is a CONTIGUOUS output run of length i+1 at
// offset tri(i) — no sqrt/div index inversion needed. Triangle load balance:
// block p handles rows p and N-1-p (combined length N+1 = 2049, constant).

#define BATCH      32
#define NFEAT      2048
#define TRI_COUNT  (NFEAT * (NFEAT + 1) / 2)      // 2,098,176
#define PER_BATCH  (NFEAT + TRI_COUNT)            // 2,100,224
#define PAIRS      (NFEAT / 2)                    // 1024 row-pairs per batch

__global__ void __launch_bounds__(256)
sideways_rows_kernel(const float* __restrict__ in, float* __restrict__ out) {
    const int blk = blockIdx.x;
    const int b   = blk >> 10;          // / PAIRS (1024)
    const int p   = blk & (PAIRS - 1);
    const int t   = threadIdx.x;

    const float* __restrict__ f  = in + b * NFEAT;
    float* __restrict__       ob = out + b * PER_BATCH;   // < 2^31 elems total

    // linear part: the p==0 block of each batch copies flat (2048 elems)
    if (p == 0) {
        for (int j = t; j < NFEAT; j += 256) ob[j] = f[j];
    }

    // row i1 = p, length p+1, contiguous at NFEAT + tri(p)
    {
        const int   i    = p;
        const float fi   = f[i];                          // wave-uniform
        float* __restrict__ orow = ob + NFEAT + ((i * (i + 1)) >> 1);
        for (int j = t; j <= i; j += 256) orow[j] = fi * f[j];
    }

    // row i2 = NFEAT-1-p, length NFEAT-p
    {
        const int   i    = NFEAT - 1 - p;
        const float fi   = f[i];
        float* __restrict__ orow = ob + NFEAT + ((i * (i + 1)) >> 1);
        for (int j = t; j <= i; j += 256) orow[j] = fi * f[j];
    }
}

extern "C" void kernel_launch(void* const* d_in, const int* in_sizes, int n_in,
                              void* d_out, int out_size, void* d_ws, size_t ws_size,
                              hipStream_t stream) {
    const float* in  = (const float*)d_in[0];
    float*       out = (float*)d_out;
    const int grid = BATCH * PAIRS;     // 32768 blocks, ~2049 stores each
    hipLaunchKernelGGL(sideways_rows_kernel, dim3(grid), dim3(256), 0, stream,
                       in, out);
}

// Round 3
// 45.410 us; speedup vs baseline: 1.7616x; 1.0232x over previous
//
#include <hip/hip_runtime.h>

// SidewaysTime: out = concat(flat, tril(outer(flat,flat))) per batch sample.
// B=32, N=2048. Output = 268.8 MB fp32 -> pure store-BW bound.
// Fill-buffer ceiling on this harness: ~6.8-7.1 TB/s.
//
// Row mapping: tril row i is a contiguous run of length i+1 at tri(i).
// Block p handles rows p and N-1-p (combined 2049 elems, constant).
// This round: float4 stores with scalar head/tail per row (tri(i) mod 4
// cycles [0,1,3,2,2,3,1,0], so rows are generally misaligned).

#define BATCH      32
#define NFEAT      2048
#define TRI_COUNT  (NFEAT * (NFEAT + 1) / 2)      // 2,098,176
#define PER_BATCH  (NFEAT + TRI_COUNT)            // 2,100,224
#define PAIRS      (NFEAT / 2)                    // 1024 row-pairs per batch

__device__ __forceinline__ void do_row(const float* __restrict__ f,
                                       float* __restrict__ otri,  // ob + NFEAT
                                       int i, int t) {
    const float fi = f[i];                         // wave-uniform
    const int   S  = (i * (i + 1)) >> 1;           // row start within tril
    float* __restrict__ orow = otri + S;
    const int   L  = i + 1;                        // row length
    int h = (4 - (S & 3)) & 3;                     // head elems to 16B align
    if (h > L) h = L;
    if (t < h) orow[t] = fi * f[t];
    const int V = (L - h) >> 2;                    // float4 groups
    for (int v = t; v < V; v += 256) {
        const int j = h + (v << 2);
        float4 o = make_float4(fi * f[j],     fi * f[j + 1],
                               fi * f[j + 2], fi * f[j + 3]);
        *reinterpret_cast<float4*>(orow + j) = o;  // 16B-aligned store
    }
    const int done = h + (V << 2);
    if (t < L - done) {                            // tail (<=3)
        const int j = done + t;
        orow[j] = fi * f[j];
    }
}

__global__ void __launch_bounds__(256)
sideways_rows_v4_kernel(const float* __restrict__ in, float* __restrict__ out) {
    const int blk = blockIdx.x;
    const int b   = blk >> 10;                     // / PAIRS
    const int p   = blk & (PAIRS - 1);
    const int t   = threadIdx.x;

    const float* __restrict__ f    = in + b * NFEAT;
    float* __restrict__       ob   = out + b * PER_BATCH;
    float* __restrict__       otri = ob + NFEAT;

    if (p == 0) {                                  // linear part, aligned
        for (int v = t; v < NFEAT / 4; v += 256)
            reinterpret_cast<float4*>(ob)[v] =
                reinterpret_cast<const float4*>(f)[v];
    }

    do_row(f, otri, p, t);                         // short row
    do_row(f, otri, NFEAT - 1 - p, t);             // long row
}

extern "C" void kernel_launch(void* const* d_in, const int* in_sizes, int n_in,
                              void* d_out, int out_size, void* d_ws, size_t ws_size,
                              hipStream_t stream) {
    const float* in  = (const float*)d_in[0];
    float*       out = (float*)d_out;
    const int grid = BATCH * PAIRS;                // 32768 blocks
    hipLaunchKernelGGL(sideways_rows_v4_kernel, dim3(grid), dim3(256), 0,
                       stream, in, out);
}